// Round 1
// baseline (414.189 us; speedup 1.0000x reference)
//
#include <hip/hip_runtime.h>

// Fused denorm + ReLU + AdaptiveAvgPool2d(56) for patch groups S=24,32,48.
// v2: 4 maps per block, double-buffered LDS, register-prefetch of map t+1
// overlapped with compute of map t (async-split staging), 1 barrier per map.
// Pool windows are <=2x2 since S < 56:
//   r0=(i*S)/56, r1=ceil((i+1)*S/56), rc=r1-r0 in {1,2} (same for cols).

#define C_CH 256
#define OUTS 56
#define NPER 32
#define MPB  4                            // maps (n,c) per block
#define BPG  ((NPER * C_CH) / MPB)        // 2048 blocks per side-group

typedef float f4 __attribute__((ext_vector_type(4)));

template<int S>
__device__ __forceinline__ void compute_map(const float* __restrict__ buf,
                                            float* __restrict__ outp) {
    const int tid = threadIdx.x;
    constexpr int NQ = (OUTS * OUTS) / 4;         // 784 float4 per output map
    f4* __restrict__ out4 = (f4*)outp;
    for (int q = tid; q < NQ; q += 256) {
        const int i  = q / (OUTS / 4);            // output row (const divisor 14)
        const int j0 = (q % (OUTS / 4)) * 4;      // first output col of this float4
        const int r0 = (i * S) / OUTS;
        const int r1 = ((i + 1) * S + OUTS - 1) / OUTS;
        const int rc = r1 - r0;                   // 1 or 2
        const float invr = (rc == 2) ? 0.5f : 1.0f;
        float o[4];
        #pragma unroll
        for (int k = 0; k < 4; ++k) {
            const int j  = j0 + k;
            const int c0 = (j * S) / OUTS;
            const int c1 = ((j + 1) * S + OUTS - 1) / OUTS;
            const int cc = c1 - c0;               // 1 or 2
            float acc = buf[r0 * S + c0];
            if (cc == 2) acc += buf[r0 * S + c0 + 1];
            if (rc == 2) {
                acc += buf[(r0 + 1) * S + c0];
                if (cc == 2) acc += buf[(r0 + 1) * S + c0 + 1];
            }
            const float invc = (cc == 2) ? 0.5f : 1.0f;
            o[k] = acc * invr * invc;             // exact: factors are powers of 2
        }
        f4 v;
        v.x = o[0]; v.y = o[1]; v.z = o[2]; v.w = o[3];
        __builtin_nontemporal_store(v, &out4[q]); // pure streaming output
    }
}

template<int S>
__device__ __forceinline__ void group_body(const float* __restrict__ x,
                                           const float* __restrict__ smean,
                                           const float* __restrict__ sstd,
                                           float* __restrict__ out,
                                           int lb, int n_base,
                                           float* __restrict__ lds) {
    constexpr int NV  = (S * S) / 4;              // float4 per input map
    constexpr int RPT = (NV + 255) / 256;         // prefetch regs (float4)/thread
    const int tid = threadIdx.x;
    const int m0  = lb * MPB;                     // first local (n,c) id

    // Per-map affine params: index is block-uniform -> scalar loads.
    float mns[MPB], sds[MPB];
    #pragma unroll
    for (int t = 0; t < MPB; ++t) {
        mns[t] = smean[(size_t)n_base * C_CH + m0 + t];
        sds[t] = sstd [(size_t)n_base * C_CH + m0 + t];
    }

    float* __restrict__ b0 = lds;
    float* __restrict__ b1 = lds + S * S;
    const f4* __restrict__ xall = (const f4*)x;   // map m lives at [m*NV, (m+1)*NV)

    f4 pref[RPT];

    // Prologue: map m0 -> b0 (latency exposed once per block only).
    #pragma unroll
    for (int u = 0; u < RPT; ++u) {
        const int idx = tid + u * 256;
        if (idx < NV) pref[u] = xall[(size_t)m0 * NV + idx];
    }
    #pragma unroll
    for (int u = 0; u < RPT; ++u) {
        const int idx = tid + u * 256;
        if (idx < NV) {
            f4 v = pref[u];
            v.x = fmaxf(fmaf(v.x, sds[0], mns[0]), 0.0f);
            v.y = fmaxf(fmaf(v.y, sds[0], mns[0]), 0.0f);
            v.z = fmaxf(fmaf(v.z, sds[0], mns[0]), 0.0f);
            v.w = fmaxf(fmaf(v.w, sds[0], mns[0]), 0.0f);
            ((f4*)b0)[idx] = v;
        }
    }
    __syncthreads();

    // Pipeline: issue loads(t+1) -> compute(t) -> denorm+ds_write(t+1) -> barrier.
    // Loads stay in flight under compute; vmcnt wait lands before the ds_write.
    // One barrier per map: stage writes the buffer compute(t) is NOT reading,
    // and the previous-iteration barrier guarantees nobody still reads it.
    #pragma unroll
    for (int t = 0; t < MPB; ++t) {
        float* const cur = (t & 1) ? b1 : b0;
        float* const nxt = (t & 1) ? b0 : b1;
        if (t + 1 < MPB) {
            #pragma unroll
            for (int u = 0; u < RPT; ++u) {
                const int idx = tid + u * 256;
                if (idx < NV) pref[u] = xall[(size_t)(m0 + t + 1) * NV + idx];
            }
        }
        compute_map<S>(cur,
            out + (size_t)((size_t)n_base * C_CH + m0 + t) * (OUTS * OUTS));
        if (t + 1 < MPB) {
            #pragma unroll
            for (int u = 0; u < RPT; ++u) {
                const int idx = tid + u * 256;
                if (idx < NV) {
                    f4 v = pref[u];
                    v.x = fmaxf(fmaf(v.x, sds[t + 1], mns[t + 1]), 0.0f);
                    v.y = fmaxf(fmaf(v.y, sds[t + 1], mns[t + 1]), 0.0f);
                    v.z = fmaxf(fmaf(v.z, sds[t + 1], mns[t + 1]), 0.0f);
                    v.w = fmaxf(fmaf(v.w, sds[t + 1], mns[t + 1]), 0.0f);
                    ((f4*)nxt)[idx] = v;
                }
            }
        }
        __syncthreads();
    }
}

__global__ __launch_bounds__(256) void PPIN_DC_20753281974843_kernel(
        const float* __restrict__ p24, const float* __restrict__ p32,
        const float* __restrict__ p48, const float* __restrict__ smean,
        const float* __restrict__ sstd, float* __restrict__ out) {
    __shared__ float lds[2 * 48 * 48];            // 18.4 KB: double buffer @ S=48
    const int bid   = blockIdx.x;
    const int group = bid >> 11;                  // / BPG (2048)
    const int lb    = bid & (BPG - 1);
    if (group == 0)      group_body<24>(p24, smean, sstd, out, lb, 0,        lds);
    else if (group == 1) group_body<32>(p32, smean, sstd, out, lb, NPER,     lds);
    else                 group_body<48>(p48, smean, sstd, out, lb, 2 * NPER, lds);
}

extern "C" void kernel_launch(void* const* d_in, const int* in_sizes, int n_in,
                              void* d_out, int out_size, void* d_ws, size_t ws_size,
                              hipStream_t stream) {
    const float* p24   = (const float*)d_in[0];
    const float* p32   = (const float*)d_in[1];
    const float* p48   = (const float*)d_in[2];
    const float* smean = (const float*)d_in[3];
    const float* sstd  = (const float*)d_in[4];
    float* out = (float*)d_out;

    // 3 groups * 2048 blocks, 4 (n,c) maps per block, pipelined.
    PPIN_DC_20753281974843_kernel<<<dim3(3 * BPG), dim3(256), 0, stream>>>(
        p24, p32, p48, smean, sstd, out);
}